// Round 4
// baseline (3041.163 us; speedup 1.0000x reference)
//
#include <hip/hip_runtime.h>
#include <hip/hip_bf16.h>

// ---------------- workspace layout (all f32) ----------------
// T2  : [256][208][14][16]   trig-expanded pooled layer-1 output (x padded to 16)
// Wr  : [21][208][13][16]    reordered conv2 weights (kx padded to 16)
// P2  : [4][256][21][14][16] conv2 partial sums over ch-quarters
// h2f : [256][1029]          pooled+flattened layer-2 output
// P3  : [65][256][89]        fk1 partial sums over d-chunks (16 d's each)
static constexpr size_t T2_OFF = 0;
static constexpr size_t T2_BYTES = (size_t)256 * 208 * 224 * 4;      // 47,710,208
static constexpr size_t WR_OFF = T2_OFF + T2_BYTES;
static constexpr size_t WR_BYTES = (size_t)21 * 208 * 208 * 4;       // 3,634,176
static constexpr size_t P2_OFF = WR_OFF + WR_BYTES;
static constexpr size_t P2_BYTES = (size_t)4 * 256 * 21 * 224 * 4;   // 19,267,584
static constexpr size_t H2_OFF = P2_OFF + P2_BYTES;
static constexpr size_t H2_BYTES = (size_t)256 * 1029 * 4;           // 1,053,696
static constexpr size_t P3_OFF = H2_OFF + H2_BYTES;

static constexpr int DCH = 16;                     // d's per fk1 chunk
static constexpr int NCH = (1029 + DCH - 1) / DCH; // 65 chunks

// ------------------------------------------------------------------
// K0: reorder conv2 weights [2][21][13][13][13][8](c,o,i,ky,kx,g) f32
//     -> Wr[o][ch][ky][kx pad16] f32 with ch = c*104 + i*8 + g
// ------------------------------------------------------------------
__global__ __launch_bounds__(256) void k_prep_w2(const float* __restrict__ w,
                                                 float* __restrict__ Wr) {
    int idx = blockIdx.x * 256 + threadIdx.x;   // over 21*208*13*16 = 908544
    if (idx >= 21 * 208 * 13 * 16) return;
    int kx = idx & 15; int t = idx >> 4;
    int ky = t % 13; t /= 13;
    int ch = t % 208; int o = t / 208;
    float v = 0.f;
    if (kx < 13) {
        int c = ch / 104; int r = ch % 104; int i = r >> 3; int g = r & 7;
        size_t src = (((((size_t)c * 21 + o) * 13 + i) * 13 + ky) * 13 + kx) * 8 + g;
        v = w[src];
    }
    Wr[idx] = v;
}

// ------------------------------------------------------------------
// K1: fused layer-1: trig-expand -> conv(5x5,G=5) -> +bias -> maxpool2
//     -> trig-expand (G=8) -> T2.  One image per block.
// ------------------------------------------------------------------
__global__ __launch_bounds__(256) void k_conv1(const float* __restrict__ x,
                                               const float* __restrict__ w1,
                                               const float* __restrict__ b1,
                                               float* __restrict__ T2) {
    __shared__ float  ximg[784];
    __shared__ float2 tcs[5][784];   // (cos, sin) per harmonic
    __shared__ float  wl[3250];      // conv1 weights f32, original layout
    __shared__ float  bl[13];
    int b = blockIdx.x, tid = threadIdx.x;
    const float* xb = x + (size_t)b * 784;
    for (int i = tid; i < 784; i += 256) ximg[i] = xb[i];
    for (int i = tid; i < 3250; i += 256) wl[i] = w1[i];
    if (tid < 13) bl[tid] = b1[tid];
    __syncthreads();
    for (int i = tid; i < 5 * 784; i += 256) {
        int g = i / 784, p = i % 784;
        float a = ximg[p] * (float)(g + 1);
        float s, c; sincosf(a, &s, &c);
        tcs[g][p] = make_float2(c, s);
    }
    __syncthreads();
    float* Tb = T2 + (size_t)b * 208 * 224;
    for (int idx = tid; idx < 13 * 196; idx += 256) {
        int o = idx / 196, p = idx % 196, py = p / 14, px = p % 14;
        float m = -1e30f;
        for (int sy = 0; sy < 2; ++sy) {
            for (int sx = 0; sx < 2; ++sx) {
                int y = 2 * py + sy, xx = 2 * px + sx;
                float v = 0.f;
                for (int ky = 0; ky < 5; ++ky) {
                    int iy = y + ky - 2;
                    if ((unsigned)iy >= 28u) continue;
                    for (int kx = 0; kx < 5; ++kx) {
                        int ix = xx + kx - 2;
                        if ((unsigned)ix >= 28u) continue;
                        int p2 = iy * 28 + ix;
                        const float* wc = &wl[(o * 25 + ky * 5 + kx) * 5];
                        const float* wsn = &wl[1625 + (o * 25 + ky * 5 + kx) * 5];
#pragma unroll
                        for (int g = 0; g < 5; ++g) {
                            float2 tv = tcs[g][p2];
                            v = fmaf(tv.x, wc[g], fmaf(tv.y, wsn[g], v));
                        }
                    }
                }
                m = fmaxf(m, v);
            }
        }
        float h = m + bl[o];
#pragma unroll
        for (int g = 0; g < 8; ++g) {
            float s, c; sincosf(h * (float)(g + 1), &s, &c);
            Tb[(size_t)(o * 8 + g) * 224 + py * 16 + px] = c;          // c=0 (cos)
            Tb[(size_t)(104 + o * 8 + g) * 224 + py * 16 + px] = s;    // c=1 (sin)
        }
    }
}

// ------------------------------------------------------------------
// K2: conv2 direct, thread = (yp,o) computes rows yp and yp+7 (uniform
//     work). ch split into 4 quarters across blocks; partials to P2.
// ------------------------------------------------------------------
__device__ __forceinline__ void rowacc(float* acc, const float* __restrict__ Trow,
                                       const float* w) {
    float r[16];
    ((float4*)r)[0] = ((const float4*)Trow)[0];
    ((float4*)r)[1] = ((const float4*)Trow)[1];
    ((float4*)r)[2] = ((const float4*)Trow)[2];
    ((float4*)r)[3] = ((const float4*)Trow)[3];
#pragma unroll
    for (int dx = 0; dx < 13; ++dx) {
        float wv = w[dx];
        const int lo = (6 - dx) < 0 ? 0 : (6 - dx);
        const int hi = (19 - dx) > 13 ? 13 : (19 - dx);
#pragma unroll
        for (int xx = lo; xx <= hi; ++xx)
            acc[xx] = fmaf(wv, r[xx + dx - 6], acc[xx]);
    }
}

__global__ __launch_bounds__(192) void k_conv2(const float* __restrict__ T2,
                                               const float* __restrict__ Wr,
                                               float* __restrict__ P2) {
    int bid = blockIdx.x;
    int b = bid >> 2, chq = bid & 3;
    int t = threadIdx.x;
    if (t >= 147) return;
    int yp = t / 21, o = t % 21;    // rows yp and yp+7
    float acc0[14], acc1[14];
#pragma unroll
    for (int i = 0; i < 14; ++i) { acc0[i] = 0.f; acc1[i] = 0.f; }
    const float* Tb = T2 + (size_t)b * 208 * 224;
    const float* Wb = Wr + (size_t)o * 208 * 208;
    int ch0 = chq * 52;
    for (int ch = ch0; ch < ch0 + 52; ++ch) {
        const float* Tch = Tb + (size_t)ch * 224;
        const float* Wch = Wb + (size_t)ch * 208;
#pragma unroll 1
        for (int dy = 0; dy < 13; ++dy) {
            float w[16];
            ((float4*)w)[0] = ((const float4*)(Wch + dy * 16))[0];
            ((float4*)w)[1] = ((const float4*)(Wch + dy * 16))[1];
            ((float4*)w)[2] = ((const float4*)(Wch + dy * 16))[2];
            ((float4*)w)[3] = ((const float4*)(Wch + dy * 16))[3];
            int y0 = yp + dy - 6;
            if ((unsigned)y0 < 14u) rowacc(acc0, Tch + y0 * 16, w);
            int y1 = y0 + 7;
            if (y1 < 14) rowacc(acc1, Tch + y1 * 16, w);   // y1 >= 1 always
        }
    }
    float* P = P2 + (((size_t)chq * 256 + b) * 21 + o) * 224;
#pragma unroll
    for (int xx = 0; xx < 14; ++xx) P[yp * 16 + xx] = acc0[xx];
#pragma unroll
    for (int xx = 0; xx < 14; ++xx) P[(yp + 7) * 16 + xx] = acc1[xx];
}

// ------------------------------------------------------------------
// K3: reduce 4 ch-quarter partials + bias -> maxpool2 -> flatten
// ------------------------------------------------------------------
__global__ __launch_bounds__(256) void k_pool2(const float* __restrict__ P2,
                                               const float* __restrict__ b2,
                                               float* __restrict__ h2f) {
    int b = blockIdx.x, tid = threadIdx.x;
    for (int idx = tid; idx < 21 * 49; idx += 256) {
        int o = idx / 49, p = idx % 49, py = p / 7, px = p % 7;
        float bias = b2[o];
        float m = -1e30f;
        for (int sy = 0; sy < 2; ++sy) {
            for (int sx = 0; sx < 2; ++sx) {
                int y = py * 2 + sy, xx = px * 2 + sx;
                float v = 0.f;
#pragma unroll
                for (int q = 0; q < 4; ++q)
                    v += P2[(((size_t)q * 256 + b) * 21 + o) * 224 + y * 16 + xx];
                m = fmaxf(m, v + bias);
            }
        }
        h2f[(size_t)b * 1029 + o * 49 + p] = m;
    }
}

// ------------------------------------------------------------------
// K4: fk1 M/K-split: block = (mt in 0..7, ks in 0..64); 32 images x
//     <=16 d's per block; trig staged in STATIC LDS [2][16*13][32] (52KB).
// ------------------------------------------------------------------
__global__ __launch_bounds__(256) void k_fk1(const float* __restrict__ h2f,
                                             const float* __restrict__ wf,
                                             float* __restrict__ P3) {
    __shared__ float trig[2][DCH * 13][32];
    int bid = blockIdx.x;
    int mt = bid / NCH, ks = bid % NCH;
    int d0 = ks * DCH;
    int dn = 1029 - d0; if (dn > DCH) dn = DCH;
    int m0 = mt * 32;
    int tid = threadIdx.x;
    for (int i = tid; i < dn * 13 * 32; i += 256) {
        int m = i & 31; int r = i >> 5; int g = r % 13; int d = r / 13;
        float xv = h2f[(size_t)(m0 + m) * 1029 + d0 + d];
        float s, c; sincosf(xv * (float)(g + 1), &s, &c);
        trig[0][d * 13 + g][m] = c;
        trig[1][d * 13 + g][m] = s;
    }
    __syncthreads();
    if (tid >= 240) return;
    int oi = tid % 30, mi = tid / 30;      // 30 o-groups x 8 m-groups
    int ob = oi * 3, mb = mi * 4;
    float acc[3][4] = {};
    for (int c = 0; c < 2; ++c) {
        const float* wc = wf + (size_t)c * 89 * 1029 * 13;
        for (int dd = 0; dd < dn; ++dd) {
            for (int g = 0; g < 13; ++g) {
                float4 tv = *(const float4*)&trig[c][dd * 13 + g][mb];
#pragma unroll
                for (int j = 0; j < 3; ++j) {
                    int o = ob + j; if (o > 88) o = 88;
                    float wv = wc[((size_t)o * 1029 + d0 + dd) * 13 + g];
                    acc[j][0] = fmaf(wv, tv.x, acc[j][0]);
                    acc[j][1] = fmaf(wv, tv.y, acc[j][1]);
                    acc[j][2] = fmaf(wv, tv.z, acc[j][2]);
                    acc[j][3] = fmaf(wv, tv.w, acc[j][3]);
                }
            }
        }
    }
#pragma unroll
    for (int j = 0; j < 3; ++j) {
        int o = ob + j; if (o > 88) continue;
#pragma unroll
        for (int mm = 0; mm < 4; ++mm)
            P3[((size_t)ks * 256 + m0 + mb + mm) * 89 + o] = acc[j][mm];
    }
}

// ------------------------------------------------------------------
// K5: reduce fk1 partials + bias -> trig (G=8) -> fk2 -> f32 out
// ------------------------------------------------------------------
__global__ __launch_bounds__(128) void k_fk2(const float* __restrict__ P3,
                                             const float* __restrict__ bias1,
                                             const float* __restrict__ wf2,
                                             const float* __restrict__ bias2,
                                             float* __restrict__ out) {
    __shared__ float2 tcs2[89][8];
    int b = blockIdx.x, tid = threadIdx.x;
    if (tid < 89) {
        float v = bias1[tid];
        for (int ks = 0; ks < NCH; ++ks)
            v += P3[((size_t)ks * 256 + b) * 89 + tid];
#pragma unroll
        for (int g = 0; g < 8; ++g) {
            float s, c; sincosf(v * (float)(g + 1), &s, &c);
            tcs2[tid][g] = make_float2(c, s);
        }
    }
    __syncthreads();
    if (tid < 10) {
        float v = bias2[tid];
        for (int d = 0; d < 89; ++d) {
#pragma unroll
            for (int g = 0; g < 8; ++g) {
                float wc = wf2[((size_t)tid * 89 + d) * 8 + g];
                float ws = wf2[(size_t)10 * 89 * 8 + ((size_t)tid * 89 + d) * 8 + g];
                float2 tv = tcs2[d][g];
                v = fmaf(tv.x, wc, fmaf(tv.y, ws, v));
            }
        }
        out[b * 10 + tid] = v;
    }
}

extern "C" void kernel_launch(void* const* d_in, const int* in_sizes, int n_in,
                              void* d_out, int out_size, void* d_ws, size_t ws_size,
                              hipStream_t stream) {
    const float* x   = (const float*)d_in[0];
    const float* w1  = (const float*)d_in[1];
    const float* b1  = (const float*)d_in[2];
    const float* w2  = (const float*)d_in[3];
    const float* b2  = (const float*)d_in[4];
    const float* wf1 = (const float*)d_in[5];
    const float* bf1 = (const float*)d_in[6];
    const float* wf2 = (const float*)d_in[7];
    const float* bf2v = (const float*)d_in[8];

    char* ws  = (char*)d_ws;
    float* T2  = (float*)(ws + T2_OFF);
    float* Wr  = (float*)(ws + WR_OFF);
    float* P2  = (float*)(ws + P2_OFF);
    float* h2f = (float*)(ws + H2_OFF);
    float* P3  = (float*)(ws + P3_OFF);

    k_prep_w2<<<(21 * 208 * 13 * 16 + 255) / 256, 256, 0, stream>>>(w2, Wr);
    k_conv1<<<256, 256, 0, stream>>>(x, w1, b1, T2);
    k_conv2<<<1024, 192, 0, stream>>>(T2, Wr, P2);
    k_pool2<<<256, 256, 0, stream>>>(P2, b2, h2f);
    k_fk1<<<8 * NCH, 256, 0, stream>>>(h2f, wf1, P3);
    k_fk2<<<256, 128, 0, stream>>>(P3, bf1, wf2, bf2v, (float*)d_out);
}

// Round 5
// 418.329 us; speedup vs baseline: 7.2698x; 7.2698x over previous
//
#include <hip/hip_runtime.h>
#include <hip/hip_bf16.h>

typedef _Float16 f16;
typedef f16  f16x8 __attribute__((ext_vector_type(8)));
typedef float f32x4 __attribute__((ext_vector_type(4)));

// ---------------- workspace layout ----------------
// h1p : [256][13][196] f32   conv1 pooled pre-activation (+bias)
// Wb2 : [13cg][85tp][2nt][64lane][8] f16  pre-packed conv2 B-fragments
// P2w : [256][8w][208p][32o] f32          conv2 per-wave partials
// h2f : [256][1029] f32
// P3  : [65][256][89] f32
static constexpr size_t H1_OFF = 0;
static constexpr size_t H1_BYTES = (size_t)256 * 13 * 196 * 4;        // 2,609,152
static constexpr size_t WB_OFF = H1_OFF + H1_BYTES;
static constexpr size_t WB_BYTES = (size_t)13 * 85 * 2 * 64 * 8 * 2;  // 2,263,040
static constexpr size_t PW_OFF = WB_OFF + WB_BYTES;
static constexpr size_t PW_BYTES = (size_t)256 * 8 * 208 * 32 * 4;    // 54,525,952
static constexpr size_t H2_OFF = PW_OFF + PW_BYTES;
static constexpr size_t H2_BYTES = (size_t)256 * 1029 * 4;            // 1,053,696
static constexpr size_t P3_OFF = H2_OFF + H2_BYTES;

static constexpr int DCH = 16;
static constexpr int NCH = (1029 + DCH - 1) / DCH; // 65

// ------------------------------------------------------------------
// K0: pack conv2 weights into per-lane mfma_16x16x32_f16 B-fragments.
// frag index = (cg*85+tp)*2+nt ; lane l ; elems i=0..7:
//   kk = (l>>4)*8+i -> tap = 2*tp + (kk>>4), ch = cg*16 + (kk&15)
//   col = l&15 -> o = nt*16+col   (zero outside tap<169, o<21)
// ------------------------------------------------------------------
__global__ __launch_bounds__(256) void k_prep_wb(const float* __restrict__ w2,
                                                 f16* __restrict__ Wb2) {
    int idx = blockIdx.x * 256 + threadIdx.x;   // over 13*85*2*64 = 141440
    if (idx >= 13 * 85 * 2 * 64) return;
    int l = idx & 63; int t = idx >> 6;
    int nt = t & 1; t >>= 1;
    int tp = t % 85; int cg = t / 85;
    int g4 = l >> 4, col = l & 15;
    int tap = 2 * tp + (g4 >> 1);
    int o = nt * 16 + col;
    f16x8 v;
#pragma unroll
    for (int i = 0; i < 8; ++i) {
        float wv = 0.f;
        if (tap < 169 && o < 21) {
            int ch = cg * 16 + (g4 & 1) * 8 + i;
            int c = ch / 104, rr = ch % 104, ii = rr >> 3, gg = rr & 7;
            int ky = tap / 13, kx = tap - ky * 13;
            wv = w2[(size_t)(c * 21 + o) * 17576 + ii * 1352 + ky * 104 + kx * 8 + gg];
        }
        v[i] = (f16)wv;
    }
    *(f16x8*)&Wb2[(size_t)idx * 8] = v;
}

// ------------------------------------------------------------------
// K1: conv1: trig-expand(G=5) -> conv5x5 -> maxpool2 -> +bias -> h1p
// ------------------------------------------------------------------
__global__ __launch_bounds__(256) void k_conv1(const float* __restrict__ x,
                                               const float* __restrict__ w1,
                                               const float* __restrict__ b1,
                                               float* __restrict__ h1p) {
    __shared__ float  ximg[784];
    __shared__ float2 tcs[5][784];
    __shared__ float  wl[3250];
    __shared__ float  bl[13];
    int b = blockIdx.x, tid = threadIdx.x;
    const float* xb = x + (size_t)b * 784;
    for (int i = tid; i < 784; i += 256) ximg[i] = xb[i];
    for (int i = tid; i < 3250; i += 256) wl[i] = w1[i];
    if (tid < 13) bl[tid] = b1[tid];
    __syncthreads();
    for (int i = tid; i < 5 * 784; i += 256) {
        int g = i / 784, p = i % 784;
        float a = ximg[p] * (float)(g + 1);
        float s, c; sincosf(a, &s, &c);
        tcs[g][p] = make_float2(c, s);
    }
    __syncthreads();
    for (int idx = tid; idx < 13 * 196; idx += 256) {
        int o = idx / 196, p = idx % 196, py = p / 14, px = p % 14;
        float m = -1e30f;
        for (int sy = 0; sy < 2; ++sy) {
            for (int sx = 0; sx < 2; ++sx) {
                int y = 2 * py + sy, xx = 2 * px + sx;
                float v = 0.f;
                for (int ky = 0; ky < 5; ++ky) {
                    int iy = y + ky - 2;
                    if ((unsigned)iy >= 28u) continue;
                    for (int kx = 0; kx < 5; ++kx) {
                        int ix = xx + kx - 2;
                        if ((unsigned)ix >= 28u) continue;
                        int p2 = iy * 28 + ix;
                        const float* wc = &wl[(o * 25 + ky * 5 + kx) * 5];
                        const float* wsn = &wl[1625 + (o * 25 + ky * 5 + kx) * 5];
#pragma unroll
                        for (int g = 0; g < 5; ++g) {
                            float2 tv = tcs[g][p2];
                            v = fmaf(tv.x, wc[g], fmaf(tv.y, wsn[g], v));
                        }
                    }
                }
                m = fmaxf(m, v);
            }
        }
        h1p[((size_t)b * 13 + o) * 196 + p] = m + bl[o];
    }
}

// ------------------------------------------------------------------
// K2: conv2 via mfma_f32_16x16x32_f16 implicit GEMM.
// Block = 1 image, 8 waves; waves split the 85 tap-pairs (K-split),
// per-wave partials to P2w.  A = on-the-fly trig expansion staged in
// zero-padded LDS [28y][32x][16ch] f16, double-buffered over 13
// ch-groups, XOR-swizzled 16B slots to break bank conflicts.
// ------------------------------------------------------------------
__global__ __launch_bounds__(512, 2) void k_conv2m(const float* __restrict__ h1p,
                                                   const f16* __restrict__ Wb2,
                                                   float* __restrict__ P2w) {
    __shared__ f16 Tl[2][28 * 32 * 16];
    const int b = blockIdx.x, tid = threadIdx.x;
    const int l = tid & 63, w = tid >> 6;

    // one-time zero of padding region (both buffers)
    for (int pos = tid; pos < 896; pos += 512) {
        int yy = pos >> 5, xx = pos & 31;
        if (yy < 6 || yy >= 20 || xx < 6 || xx >= 20) {
            f16x8 z = {};
            *(f16x8*)&Tl[0][(yy * 32 + xx) * 16] = z;
            *(f16x8*)&Tl[0][(yy * 32 + xx) * 16 + 8] = z;
            *(f16x8*)&Tl[1][(yy * 32 + xx) * 16] = z;
            *(f16x8*)&Tl[1][(yy * 32 + xx) * 16 + 8] = z;
        }
    }

    auto stage = [&](int cg, int bufn) {
        if (tid < 392) {
            int p = tid >> 1, oct = tid & 1;
            int ch0 = cg * 16 + oct * 8;
            int c = ch0 / 104, rr = ch0 % 104, ii = rr >> 3;
            float h = h1p[((size_t)b * 13 + ii) * 196 + p];
            float s1, c1;
            __sincosf(h, &s1, &c1);
            f16x8 v;
            float ck = c1, sk = s1, ckm = 1.f, skm = 0.f;
#pragma unroll
            for (int g = 0; g < 8; ++g) {
                v[g] = (f16)(c == 0 ? ck : sk);
                float cn = 2.f * c1 * ck - ckm;
                float sn2 = 2.f * c1 * sk - skm;
                ckm = ck; ck = cn; skm = sk; sk = sn2;
            }
            int y = p / 14;
            int yy = y + 6, xx = p - y * 14 + 6;
            int slot = oct ^ (((xx >> 2) ^ yy) & 1);
            *(f16x8*)&Tl[bufn][(yy * 32 + xx) * 16 + slot * 8] = v;
        }
    };

    stage(0, 0);

    const int g4 = l >> 4, col = l & 15;
    const int tapoff = g4 >> 1, slotg = g4 & 1;
    int ybase[13], xbase[13];
#pragma unroll
    for (int m = 0; m < 13; ++m) {
        int p = m * 16 + col; if (p > 195) p = 195;
        ybase[m] = p / 14;
        xbase[m] = p - ybase[m] * 14;
    }

    f32x4 acc[13][2] = {};
    const int tp0 = (w * 85) >> 3, tp1 = ((w + 1) * 85) >> 3;
    __syncthreads();

    for (int cg = 0; cg < 13; ++cg) {
        const int bufn = cg & 1;
        if (cg + 1 < 13) stage(cg + 1, bufn ^ 1);
        const f16* Tb = &Tl[bufn][0];
        for (int tp = tp0; tp < tp1; ++tp) {
            f16x8 bf0 = *(const f16x8*)&Wb2[((size_t)((cg * 85 + tp) * 2 + 0) * 64 + l) * 8];
            f16x8 bf1 = *(const f16x8*)&Wb2[((size_t)((cg * 85 + tp) * 2 + 1) * 64 + l) * 8];
            int tap = 2 * tp + tapoff;
            int ky = tap / 13, kx = tap - ky * 13;
#pragma unroll
            for (int m = 0; m < 13; ++m) {
                int yy = ybase[m] + ky, xx = xbase[m] + kx;
                int slot = slotg ^ (((xx >> 2) ^ yy) & 1);
                f16x8 a = *(const f16x8*)&Tb[(yy * 32 + xx) * 16 + slot * 8];
                acc[m][0] = __builtin_amdgcn_mfma_f32_16x16x32_f16(a, bf0, acc[m][0], 0, 0, 0);
                acc[m][1] = __builtin_amdgcn_mfma_f32_16x16x32_f16(a, bf1, acc[m][1], 0, 0, 0);
            }
        }
        __syncthreads();
    }

    // epilogue: C/D layout col=l&15, row=(l>>4)*4+j
    float* Pb = P2w + ((size_t)b * 8 + w) * 208 * 32;
#pragma unroll
    for (int m = 0; m < 13; ++m)
#pragma unroll
        for (int nt = 0; nt < 2; ++nt)
#pragma unroll
            for (int j = 0; j < 4; ++j) {
                int p = m * 16 + (l >> 4) * 4 + j;
                int o = nt * 16 + col;
                Pb[p * 32 + o] = acc[m][nt][j];
            }
}

// ------------------------------------------------------------------
// K3: reduce 8 wave-partials + bias -> maxpool2 -> flatten
// ------------------------------------------------------------------
__global__ __launch_bounds__(256) void k_pool2(const float* __restrict__ P2w,
                                               const float* __restrict__ b2,
                                               float* __restrict__ h2f) {
    int b = blockIdx.x, tid = threadIdx.x;
    for (int idx = tid; idx < 1029; idx += 256) {
        int o = idx % 21, pp = idx / 21;
        int py = pp / 7, px = pp % 7;
        float m = -1e30f;
        for (int sy = 0; sy < 2; ++sy)
            for (int sx = 0; sx < 2; ++sx) {
                int p = (2 * py + sy) * 14 + 2 * px + sx;
                float v = 0.f;
#pragma unroll
                for (int w = 0; w < 8; ++w)
                    v += P2w[(((size_t)b * 8 + w) * 208 + p) * 32 + o];
                m = fmaxf(m, v);
            }
        h2f[(size_t)b * 1029 + o * 49 + pp] = m + b2[o];
    }
}

// ------------------------------------------------------------------
// K4: fk1 M/K-split (unchanged from round 4)
// ------------------------------------------------------------------
__global__ __launch_bounds__(256) void k_fk1(const float* __restrict__ h2f,
                                             const float* __restrict__ wf,
                                             float* __restrict__ P3) {
    __shared__ float trig[2][DCH * 13][32];
    int bid = blockIdx.x;
    int mt = bid / NCH, ks = bid % NCH;
    int d0 = ks * DCH;
    int dn = 1029 - d0; if (dn > DCH) dn = DCH;
    int m0 = mt * 32;
    int tid = threadIdx.x;
    for (int i = tid; i < dn * 13 * 32; i += 256) {
        int m = i & 31; int r = i >> 5; int g = r % 13; int d = r / 13;
        float xv = h2f[(size_t)(m0 + m) * 1029 + d0 + d];
        float s, c; sincosf(xv * (float)(g + 1), &s, &c);
        trig[0][d * 13 + g][m] = c;
        trig[1][d * 13 + g][m] = s;
    }
    __syncthreads();
    if (tid >= 240) return;
    int oi = tid % 30, mi = tid / 30;
    int ob = oi * 3, mb = mi * 4;
    float acc[3][4] = {};
    for (int c = 0; c < 2; ++c) {
        const float* wc = wf + (size_t)c * 89 * 1029 * 13;
        for (int dd = 0; dd < dn; ++dd) {
            for (int g = 0; g < 13; ++g) {
                float4 tv = *(const float4*)&trig[c][dd * 13 + g][mb];
#pragma unroll
                for (int j = 0; j < 3; ++j) {
                    int o = ob + j; if (o > 88) o = 88;
                    float wv = wc[((size_t)o * 1029 + d0 + dd) * 13 + g];
                    acc[j][0] = fmaf(wv, tv.x, acc[j][0]);
                    acc[j][1] = fmaf(wv, tv.y, acc[j][1]);
                    acc[j][2] = fmaf(wv, tv.z, acc[j][2]);
                    acc[j][3] = fmaf(wv, tv.w, acc[j][3]);
                }
            }
        }
    }
#pragma unroll
    for (int j = 0; j < 3; ++j) {
        int o = ob + j; if (o > 88) continue;
#pragma unroll
        for (int mm = 0; mm < 4; ++mm)
            P3[((size_t)ks * 256 + m0 + mb + mm) * 89 + o] = acc[j][mm];
    }
}

// ------------------------------------------------------------------
// K5: reduce fk1 partials + bias -> trig(G=8) -> fk2 -> f32 out
// ------------------------------------------------------------------
__global__ __launch_bounds__(128) void k_fk2(const float* __restrict__ P3,
                                             const float* __restrict__ bias1,
                                             const float* __restrict__ wf2,
                                             const float* __restrict__ bias2,
                                             float* __restrict__ out) {
    __shared__ float2 tcs2[89][8];
    int b = blockIdx.x, tid = threadIdx.x;
    if (tid < 89) {
        float v = bias1[tid];
        for (int ks = 0; ks < NCH; ++ks)
            v += P3[((size_t)ks * 256 + b) * 89 + tid];
#pragma unroll
        for (int g = 0; g < 8; ++g) {
            float s, c; sincosf(v * (float)(g + 1), &s, &c);
            tcs2[tid][g] = make_float2(c, s);
        }
    }
    __syncthreads();
    if (tid < 10) {
        float v = bias2[tid];
        for (int d = 0; d < 89; ++d) {
#pragma unroll
            for (int g = 0; g < 8; ++g) {
                float wc = wf2[((size_t)tid * 89 + d) * 8 + g];
                float ws = wf2[(size_t)10 * 89 * 8 + ((size_t)tid * 89 + d) * 8 + g];
                float2 tv = tcs2[d][g];
                v = fmaf(tv.x, wc, fmaf(tv.y, ws, v));
            }
        }
        out[b * 10 + tid] = v;
    }
}

extern "C" void kernel_launch(void* const* d_in, const int* in_sizes, int n_in,
                              void* d_out, int out_size, void* d_ws, size_t ws_size,
                              hipStream_t stream) {
    const float* x   = (const float*)d_in[0];
    const float* w1  = (const float*)d_in[1];
    const float* b1  = (const float*)d_in[2];
    const float* w2  = (const float*)d_in[3];
    const float* b2  = (const float*)d_in[4];
    const float* wf1 = (const float*)d_in[5];
    const float* bf1 = (const float*)d_in[6];
    const float* wf2 = (const float*)d_in[7];
    const float* bf2v = (const float*)d_in[8];

    char* ws  = (char*)d_ws;
    float* h1p = (float*)(ws + H1_OFF);
    f16*   Wb2 = (f16*)(ws + WB_OFF);
    float* P2w = (float*)(ws + PW_OFF);
    float* h2f = (float*)(ws + H2_OFF);
    float* P3  = (float*)(ws + P3_OFF);

    k_prep_wb<<<(13 * 85 * 2 * 64 + 255) / 256, 256, 0, stream>>>(w2, Wb2);
    k_conv1<<<256, 256, 0, stream>>>(x, w1, b1, h1p);
    k_conv2m<<<256, 512, 0, stream>>>(h1p, Wb2, P2w);
    k_pool2<<<256, 256, 0, stream>>>(P2w, b2, h2f);
    k_fk1<<<8 * NCH, 256, 0, stream>>>(h2f, wf1, P3);
    k_fk2<<<256, 128, 0, stream>>>(P3, bf1, wf2, bf2v, (float*)d_out);
}

// Round 6
// 347.824 us; speedup vs baseline: 8.7434x; 1.2027x over previous
//
#include <hip/hip_runtime.h>
#include <hip/hip_bf16.h>

typedef _Float16 f16;
typedef f16  f16x8 __attribute__((ext_vector_type(8)));
typedef float f32x4 __attribute__((ext_vector_type(4)));

// ---------------- workspace layout ----------------
// h1p : [256][13][196] f32   conv1 pooled pre-activation (+bias)
// Wb2 : [13cg][85tp][2nt][64lane][8] f16  pre-packed conv2 B-fragments
// h2f : [256][1029] f32
// P3  : [65][256][89] f32
static constexpr size_t H1_OFF = 0;
static constexpr size_t H1_BYTES = (size_t)256 * 13 * 196 * 4;        // 2,609,152
static constexpr size_t WB_OFF = H1_OFF + H1_BYTES;
static constexpr size_t WB_BYTES = (size_t)13 * 85 * 2 * 64 * 8 * 2;  // 2,263,040
static constexpr size_t H2_OFF = WB_OFF + WB_BYTES;
static constexpr size_t H2_BYTES = (size_t)256 * 1029 * 4;            // 1,053,696
static constexpr size_t P3_OFF = H2_OFF + H2_BYTES;

static constexpr int DCH = 16;
static constexpr int NCH = (1029 + DCH - 1) / DCH; // 65

// ------------------------------------------------------------------
// K0: pack conv2 weights into per-lane mfma_16x16x32_f16 B-fragments.
//   kk = (l>>4)*8+i -> tap = 2*tp + (kk>>4), ch = cg*16 + (kk&15)
//   col = l&15 -> o = nt*16+col   (zero outside tap<169, o<21)
// ------------------------------------------------------------------
__global__ __launch_bounds__(256) void k_prep_wb(const float* __restrict__ w2,
                                                 f16* __restrict__ Wb2) {
    int idx = blockIdx.x * 256 + threadIdx.x;   // over 13*85*2*64 = 141440
    if (idx >= 13 * 85 * 2 * 64) return;
    int l = idx & 63; int t = idx >> 6;
    int nt = t & 1; t >>= 1;
    int tp = t % 85; int cg = t / 85;
    int g4 = l >> 4, col = l & 15;
    int tap = 2 * tp + (g4 >> 1);
    int o = nt * 16 + col;
    f16x8 v;
#pragma unroll
    for (int i = 0; i < 8; ++i) {
        float wv = 0.f;
        if (tap < 169 && o < 21) {
            int ch = cg * 16 + (g4 & 1) * 8 + i;
            int c = ch / 104, rr = ch % 104, ii = rr >> 3, gg = rr & 7;
            int ky = tap / 13, kx = tap - ky * 13;
            wv = w2[(size_t)(c * 21 + o) * 17576 + ii * 1352 + ky * 104 + kx * 8 + gg];
        }
        v[i] = (f16)wv;
    }
    *(f16x8*)&Wb2[(size_t)idx * 8] = v;
}

// ------------------------------------------------------------------
// K1: conv1: trig-expand(G=5) -> conv5x5 -> maxpool2 -> +bias -> h1p
//     2 blocks per image (o-split) for occupancy.
// ------------------------------------------------------------------
__global__ __launch_bounds__(256) void k_conv1(const float* __restrict__ x,
                                               const float* __restrict__ w1,
                                               const float* __restrict__ b1,
                                               float* __restrict__ h1p) {
    __shared__ float  ximg[784];
    __shared__ float2 tcs[5][784];
    __shared__ float  wl[3250];
    __shared__ float  bl[13];
    int bid = blockIdx.x, tid = threadIdx.x;
    int b = bid >> 1, half = bid & 1;
    int o0 = half * 7, ocnt = half ? 6 : 7;
    const float* xb = x + (size_t)b * 784;
    for (int i = tid; i < 784; i += 256) ximg[i] = xb[i];
    for (int i = tid; i < 3250; i += 256) wl[i] = w1[i];
    if (tid < 13) bl[tid] = b1[tid];
    __syncthreads();
    for (int i = tid; i < 5 * 784; i += 256) {
        int g = i / 784, p = i % 784;
        float a = ximg[p] * (float)(g + 1);
        float s, c; sincosf(a, &s, &c);
        tcs[g][p] = make_float2(c, s);
    }
    __syncthreads();
    for (int idx = tid; idx < ocnt * 196; idx += 256) {
        int o = o0 + idx / 196, p = idx % 196, py = p / 14, px = p % 14;
        float m = -1e30f;
        for (int sy = 0; sy < 2; ++sy) {
            for (int sx = 0; sx < 2; ++sx) {
                int y = 2 * py + sy, xx = 2 * px + sx;
                float v = 0.f;
                for (int ky = 0; ky < 5; ++ky) {
                    int iy = y + ky - 2;
                    if ((unsigned)iy >= 28u) continue;
                    for (int kx = 0; kx < 5; ++kx) {
                        int ix = xx + kx - 2;
                        if ((unsigned)ix >= 28u) continue;
                        int p2 = iy * 28 + ix;
                        const float* wc = &wl[(o * 25 + ky * 5 + kx) * 5];
                        const float* wsn = &wl[1625 + (o * 25 + ky * 5 + kx) * 5];
#pragma unroll
                        for (int g = 0; g < 5; ++g) {
                            float2 tv = tcs[g][p2];
                            v = fmaf(tv.x, wc[g], fmaf(tv.y, wsn[g], v));
                        }
                    }
                }
                m = fmaxf(m, v);
            }
        }
        h1p[((size_t)b * 13 + o) * 196 + p] = m + bl[o];
    }
}

// ------------------------------------------------------------------
// K2: conv2 implicit-GEMM MFMA + fused reduce + bias + maxpool -> h2f.
// M-tile = one output row (y) padded to 16 cols -> 14 tiles; 8 waves
// K-split over 85 tap-pairs; tree reduction in LDS after K-loop.
// ------------------------------------------------------------------
__global__ __launch_bounds__(512, 2) void k_conv2m(const float* __restrict__ h1p,
                                                   const f16* __restrict__ Wb2,
                                                   const float* __restrict__ b2,
                                                   float* __restrict__ h2f) {
    __shared__ f16 Tl[2][28 * 32 * 16];
    const int b = blockIdx.x, tid = threadIdx.x;
    const int l = tid & 63, w = tid >> 6;

    // zero the halo once (both buffers)
    for (int pos = tid; pos < 896; pos += 512) {
        int yy = pos >> 5, xx = pos & 31;
        if (yy < 6 || yy >= 20 || xx < 6 || xx >= 20) {
            f16x8 z = {};
            *(f16x8*)&Tl[0][(yy * 32 + xx) * 16] = z;
            *(f16x8*)&Tl[0][(yy * 32 + xx) * 16 + 8] = z;
            *(f16x8*)&Tl[1][(yy * 32 + xx) * 16] = z;
            *(f16x8*)&Tl[1][(yy * 32 + xx) * 16 + 8] = z;
        }
    }

    auto stage = [&](int cg, int bufn) {
        if (tid < 392) {
            int p = tid >> 1, oct = tid & 1;
            int ch0 = cg * 16 + oct * 8;
            int c = ch0 / 104, rr = ch0 % 104, ii = rr >> 3;
            float h = h1p[((size_t)b * 13 + ii) * 196 + p];
            float s1, c1;
            __sincosf(h, &s1, &c1);
            f16x8 v;
            float ck = c1, sk = s1, ckm = 1.f, skm = 0.f;
#pragma unroll
            for (int g = 0; g < 8; ++g) {
                v[g] = (f16)(c == 0 ? ck : sk);
                float cn = 2.f * c1 * ck - ckm;
                float sn2 = 2.f * c1 * sk - skm;
                ckm = ck; ck = cn; skm = sk; sk = sn2;
            }
            int y = p / 14, xp = p - y * 14;
            int yy = y + 6, xx = xp + 6;
            int slot = oct ^ (((xx >> 2) ^ yy) & 1);
            *(f16x8*)&Tl[bufn][((yy * 32 + xx) * 2 + slot) * 8] = v;
        }
    };

    stage(0, 0);
    const int g4 = l >> 4, col = l & 15;
    const int tapoff = g4 >> 1, slotg = g4 & 1;
    f32x4 acc[14][2] = {};
    const int tp0 = (w * 85) >> 3, tp1 = ((w + 1) * 85) >> 3;
    __syncthreads();

    for (int cg = 0; cg < 13; ++cg) {
        const int bufn = cg & 1;
        if (cg + 1 < 13) stage(cg + 1, bufn ^ 1);
        const f16* Tb = &Tl[bufn][0];
        for (int tp = tp0; tp < tp1; ++tp) {
            f16x8 bf0 = *(const f16x8*)&Wb2[((size_t)((cg * 85 + tp) * 2 + 0) * 64 + l) * 8];
            f16x8 bf1 = *(const f16x8*)&Wb2[((size_t)((cg * 85 + tp) * 2 + 1) * 64 + l) * 8];
            int tap = 2 * tp + tapoff;
            int ky = tap / 13, kx = tap - ky * 13;  // tap==169 -> ky=13 -> rows >=20 (zeroed halo)
            int xx = col + kx;
            int sl0 = slotg ^ (((xx >> 2) ^ ky) & 1);
            int base = xx * 2;
#pragma unroll
            for (int m = 0; m < 14; ++m) {
                int yy = m + ky;
                int slot = sl0 ^ (m & 1);
                f16x8 a = *(const f16x8*)&Tb[((yy * 64 + base) + slot) * 8];
                acc[m][0] = __builtin_amdgcn_mfma_f32_16x16x32_f16(a, bf0, acc[m][0], 0, 0, 0);
                acc[m][1] = __builtin_amdgcn_mfma_f32_16x16x32_f16(a, bf1, acc[m][1], 0, 0, 0);
            }
        }
        __syncthreads();
    }

    // tree reduction: waves 0-3 -> R0, waves 4-7 -> R1 (fixed phase order)
    float* R0 = (float*)&Tl[0][0];   // [14*16][32] = 28,672 B
    float* R1 = (float*)&Tl[1][0];
    float* Rw = (w < 4) ? R0 : R1;
    const int wph = w & 3;
    for (int ph = 0; ph < 4; ++ph) {
        if (wph == ph) {
#pragma unroll
            for (int m = 0; m < 14; ++m)
#pragma unroll
                for (int nt = 0; nt < 2; ++nt)
#pragma unroll
                    for (int j = 0; j < 4; ++j) {
                        int idx = (m * 16 + g4 * 4 + j) * 32 + nt * 16 + col;
                        float v = acc[m][nt][j];
                        if (ph) v += Rw[idx];
                        Rw[idx] = v;
                    }
        }
        __syncthreads();
    }

    // pool 2x2 + bias -> h2f (rows=y index m, in-tile row = x)
    for (int idx = tid; idx < 1029; idx += 512) {
        int o = idx % 21; int r = idx / 21; int px = r % 7; int py = r / 7;
        float mx = -1e30f;
#pragma unroll
        for (int sy = 0; sy < 2; ++sy)
#pragma unroll
            for (int sx = 0; sx < 2; ++sx) {
                int ii = ((py * 2 + sy) * 16 + px * 2 + sx) * 32 + o;
                mx = fmaxf(mx, R0[ii] + R1[ii]);
            }
        h2f[(size_t)b * 1029 + o * 49 + py * 7 + px] = mx + b2[o];
    }
}

// ------------------------------------------------------------------
// K4: fk1 M/K-split: block = (mt 0..7, ks 0..64); 32 images x <=16 d's;
//     trig staged in static LDS [2][16*13][32] (52KB).
// ------------------------------------------------------------------
__global__ __launch_bounds__(256) void k_fk1(const float* __restrict__ h2f,
                                             const float* __restrict__ wf,
                                             float* __restrict__ P3) {
    __shared__ float trig[2][DCH * 13][32];
    int bid = blockIdx.x;
    int mt = bid / NCH, ks = bid % NCH;
    int d0 = ks * DCH;
    int dn = 1029 - d0; if (dn > DCH) dn = DCH;
    int m0 = mt * 32;
    int tid = threadIdx.x;
    for (int i = tid; i < dn * 13 * 32; i += 256) {
        int m = i & 31; int r = i >> 5; int g = r % 13; int d = r / 13;
        float xv = h2f[(size_t)(m0 + m) * 1029 + d0 + d];
        float s, c; sincosf(xv * (float)(g + 1), &s, &c);
        trig[0][d * 13 + g][m] = c;
        trig[1][d * 13 + g][m] = s;
    }
    __syncthreads();
    if (tid >= 240) return;
    int oi = tid % 30, mi = tid / 30;
    int ob = oi * 3, mb = mi * 4;
    float acc[3][4] = {};
    for (int c = 0; c < 2; ++c) {
        const float* wc = wf + (size_t)c * 89 * 1029 * 13;
        for (int dd = 0; dd < dn; ++dd) {
            for (int g = 0; g < 13; ++g) {
                float4 tv = *(const float4*)&trig[c][dd * 13 + g][mb];
#pragma unroll
                for (int j = 0; j < 3; ++j) {
                    int o = ob + j; if (o > 88) o = 88;
                    float wv = wc[((size_t)o * 1029 + d0 + dd) * 13 + g];
                    acc[j][0] = fmaf(wv, tv.x, acc[j][0]);
                    acc[j][1] = fmaf(wv, tv.y, acc[j][1]);
                    acc[j][2] = fmaf(wv, tv.z, acc[j][2]);
                    acc[j][3] = fmaf(wv, tv.w, acc[j][3]);
                }
            }
        }
    }
#pragma unroll
    for (int j = 0; j < 3; ++j) {
        int o = ob + j; if (o > 88) continue;
#pragma unroll
        for (int mm = 0; mm < 4; ++mm)
            P3[((size_t)ks * 256 + m0 + mb + mm) * 89 + o] = acc[j][mm];
    }
}

// ------------------------------------------------------------------
// K5: reduce fk1 partials + bias -> trig(G=8) -> fk2 -> f32 out
// ------------------------------------------------------------------
__global__ __launch_bounds__(128) void k_fk2(const float* __restrict__ P3,
                                             const float* __restrict__ bias1,
                                             const float* __restrict__ wf2,
                                             const float* __restrict__ bias2,
                                             float* __restrict__ out) {
    __shared__ float2 tcs2[89][8];
    int b = blockIdx.x, tid = threadIdx.x;
    if (tid < 89) {
        float v = bias1[tid];
        for (int ks = 0; ks < NCH; ++ks)
            v += P3[((size_t)ks * 256 + b) * 89 + tid];
#pragma unroll
        for (int g = 0; g < 8; ++g) {
            float s, c; sincosf(v * (float)(g + 1), &s, &c);
            tcs2[tid][g] = make_float2(c, s);
        }
    }
    __syncthreads();
    if (tid < 10) {
        float v = bias2[tid];
        for (int d = 0; d < 89; ++d) {
#pragma unroll
            for (int g = 0; g < 8; ++g) {
                float wc = wf2[((size_t)tid * 89 + d) * 8 + g];
                float ws = wf2[(size_t)10 * 89 * 8 + ((size_t)tid * 89 + d) * 8 + g];
                float2 tv = tcs2[d][g];
                v = fmaf(tv.x, wc, fmaf(tv.y, ws, v));
            }
        }
        out[b * 10 + tid] = v;
    }
}

extern "C" void kernel_launch(void* const* d_in, const int* in_sizes, int n_in,
                              void* d_out, int out_size, void* d_ws, size_t ws_size,
                              hipStream_t stream) {
    const float* x   = (const float*)d_in[0];
    const float* w1  = (const float*)d_in[1];
    const float* b1  = (const float*)d_in[2];
    const float* w2  = (const float*)d_in[3];
    const float* b2  = (const float*)d_in[4];
    const float* wf1 = (const float*)d_in[5];
    const float* bf1 = (const float*)d_in[6];
    const float* wf2 = (const float*)d_in[7];
    const float* bf2v = (const float*)d_in[8];

    char* ws  = (char*)d_ws;
    float* h1p = (float*)(ws + H1_OFF);
    f16*   Wb2 = (f16*)(ws + WB_OFF);
    float* h2f = (float*)(ws + H2_OFF);
    float* P3  = (float*)(ws + P3_OFF);

    k_prep_wb<<<(13 * 85 * 2 * 64 + 255) / 256, 256, 0, stream>>>(w2, Wb2);
    k_conv1<<<512, 256, 0, stream>>>(x, w1, b1, h1p);
    k_conv2m<<<256, 512, 0, stream>>>(h1p, Wb2, b2, h2f);
    k_fk1<<<8 * NCH, 256, 0, stream>>>(h2f, wf1, P3);
    k_fk2<<<256, 128, 0, stream>>>(P3, bf1, wf2, bf2v, (float*)d_out);
}

// Round 7
// 258.198 us; speedup vs baseline: 11.7784x; 1.3471x over previous
//
#include <hip/hip_runtime.h>
#include <hip/hip_bf16.h>

typedef _Float16 f16;
typedef f16  f16x8 __attribute__((ext_vector_type(8)));
typedef float f32x4 __attribute__((ext_vector_type(4)));

// ---------------- workspace layout ----------------
// h1p  : [256][13][196] f32  conv1 pooled pre-activation (+bias)
// Wb2  : [13cg][13kx][7p][2nt][64l][8] f16  conv2 B-fragments (K = 2rows x 16ch)
// Wf1b : [33ks][26kstep][6nt][64l][8] f16   fk1 B-fragments  (K = 32 d)
// h2f  : [256][1029] f32
// P3   : [33][256][89] f32   fk1 partials over d-chunks
static constexpr size_t H1_OFF = 0;
static constexpr size_t H1_BYTES = (size_t)256 * 13 * 196 * 4;            // 2,609,152
static constexpr size_t WB_OFF = H1_OFF + H1_BYTES;
static constexpr size_t WB_BYTES = (size_t)13 * 13 * 7 * 2 * 64 * 8 * 2;  // 2,422,784
static constexpr size_t WF_OFF = WB_OFF + WB_BYTES;
static constexpr size_t WF_BYTES = (size_t)33 * 26 * 6 * 64 * 8 * 2;      // 5,271,552
static constexpr size_t H2_OFF = WF_OFF + WF_BYTES;
static constexpr size_t H2_BYTES = (size_t)256 * 1029 * 4;                // 1,053,696
static constexpr size_t P3_OFF = H2_OFF + H2_BYTES;

static constexpr int NCH = 33;   // fk1 d-chunks of 32 (last = 5)

// ------------------------------------------------------------------
// K0: conv2 B-fragments.  frag (cg,kx,p,nt), lane l, elems i:
//   oct=l>>4: ky = 2p+(oct>>1), ch = cg*16+(oct&1)*8+i, o = nt*16+(l&15)
//   zero when ky>12 or o>20.
// ------------------------------------------------------------------
__global__ __launch_bounds__(256) void k_prep_wb(const float* __restrict__ w2,
                                                 f16* __restrict__ Wb2) {
    int idx = blockIdx.x * 256 + threadIdx.x;   // over 13*13*7*2*64 = 151424
    if (idx >= 13 * 13 * 7 * 2 * 64) return;
    int l = idx & 63; int t = idx >> 6;
    int nt = t & 1; t >>= 1;
    int p = t % 7; t /= 7;
    int kx = t % 13; int cg = t / 13;
    int oct = l >> 4, col = l & 15;
    int ky = 2 * p + (oct >> 1);
    int o = nt * 16 + col;
    f16x8 v;
#pragma unroll
    for (int i = 0; i < 8; ++i) {
        float wv = 0.f;
        if (ky < 13 && o < 21) {
            int ch = cg * 16 + (oct & 1) * 8 + i;
            int c2 = ch / 104, rr = ch % 104, ii = rr >> 3, gg = rr & 7;
            wv = w2[(size_t)(c2 * 21 + o) * 17576 + ii * 1352 + ky * 104 + kx * 8 + gg];
        }
        v[i] = (f16)wv;
    }
    *(f16x8*)&Wb2[(size_t)idx * 8] = v;
}

// ------------------------------------------------------------------
// K0b: fk1 B-fragments.  frag (ks,kstep,nt): kstep=(c*13+g);
//   lane l elems i: d = ks*32+(l>>4)*8+i, o = nt*16+(l&15).
// ------------------------------------------------------------------
__global__ __launch_bounds__(256) void k_prep_wf(const float* __restrict__ wf1,
                                                 f16* __restrict__ Wf1b) {
    int idx = blockIdx.x * 256 + threadIdx.x;   // over 33*26*6*64 = 329472
    if (idx >= 33 * 26 * 6 * 64) return;
    int l = idx & 63; int t = idx >> 6;
    int nt = t % 6; t /= 6;
    int kstep = t % 26; int ks = t / 26;
    int c = kstep / 13, g = kstep % 13;
    int o = nt * 16 + (l & 15);
    f16x8 v;
#pragma unroll
    for (int i = 0; i < 8; ++i) {
        int d = ks * 32 + (l >> 4) * 8 + i;
        float wv = (d < 1029 && o < 89) ? wf1[((size_t)(c * 89 + o) * 1029 + d) * 13 + g] : 0.f;
        v[i] = (f16)wv;
    }
    *(f16x8*)&Wf1b[(size_t)idx * 8] = v;
}

// ------------------------------------------------------------------
// K1: conv1: trig(G=5) -> conv5x5 -> maxpool2 -> +bias -> h1p
// ------------------------------------------------------------------
__global__ __launch_bounds__(256) void k_conv1(const float* __restrict__ x,
                                               const float* __restrict__ w1,
                                               const float* __restrict__ b1,
                                               float* __restrict__ h1p) {
    __shared__ float  ximg[784];
    __shared__ float2 tcs[5][784];
    __shared__ float  wl[3250];
    __shared__ float  bl[13];
    int bid = blockIdx.x, tid = threadIdx.x;
    int b = bid >> 1, half = bid & 1;
    int o0 = half * 7, ocnt = half ? 6 : 7;
    const float* xb = x + (size_t)b * 784;
    for (int i = tid; i < 784; i += 256) ximg[i] = xb[i];
    for (int i = tid; i < 3250; i += 256) wl[i] = w1[i];
    if (tid < 13) bl[tid] = b1[tid];
    __syncthreads();
    for (int i = tid; i < 5 * 784; i += 256) {
        int g = i / 784, p = i % 784;
        float a = ximg[p] * (float)(g + 1);
        float s, c; sincosf(a, &s, &c);
        tcs[g][p] = make_float2(c, s);
    }
    __syncthreads();
    for (int idx = tid; idx < ocnt * 196; idx += 256) {
        int o = o0 + idx / 196, p = idx % 196, py = p / 14, px = p % 14;
        float m = -1e30f;
        for (int sy = 0; sy < 2; ++sy) {
            for (int sx = 0; sx < 2; ++sx) {
                int y = 2 * py + sy, xx = 2 * px + sx;
                float v = 0.f;
                for (int ky = 0; ky < 5; ++ky) {
                    int iy = y + ky - 2;
                    if ((unsigned)iy >= 28u) continue;
                    for (int kx = 0; kx < 5; ++kx) {
                        int ix = xx + kx - 2;
                        if ((unsigned)ix >= 28u) continue;
                        int p2 = iy * 28 + ix;
                        const float* wc = &wl[(o * 25 + ky * 5 + kx) * 5];
                        const float* wsn = &wl[1625 + (o * 25 + ky * 5 + kx) * 5];
#pragma unroll
                        for (int g = 0; g < 5; ++g) {
                            float2 tv = tcs[g][p2];
                            v = fmaf(tv.x, wc[g], fmaf(tv.y, wsn[g], v));
                        }
                    }
                }
                m = fmaxf(m, v);
            }
        }
        h1p[((size_t)b * 13 + o) * 196 + p] = m + bl[o];
    }
}

// ------------------------------------------------------------------
// K2: conv2 MFMA, register-held B, A-reuse across ky-pairs.
// K = 2 input rows x 16 ch.  Waves split kx (0..12).  Fully unrolled
// yy0 loop keeps acc[] statically indexed.  Fused reduce+pool+bias.
// ------------------------------------------------------------------
__global__ __launch_bounds__(512, 2) void k_conv2m(const float* __restrict__ h1p,
                                                   const f16* __restrict__ Wb2,
                                                   const float* __restrict__ b2,
                                                   float* __restrict__ h2f) {
    __shared__ f16 Tl[2][28 * 32 * 16];
    const int b = blockIdx.x, tid = threadIdx.x;
    const int l = tid & 63, w = tid >> 6;
    const int oct = l >> 4, col = l & 15;

    // zero halo once (both buffers)
    for (int pos = tid; pos < 896; pos += 512) {
        int yy = pos >> 5, xx = pos & 31;
        if (yy < 6 || yy >= 20 || xx < 6 || xx >= 20) {
            f16x8 z = {};
            *(f16x8*)&Tl[0][(yy * 32 + xx) * 16] = z;
            *(f16x8*)&Tl[0][(yy * 32 + xx) * 16 + 8] = z;
            *(f16x8*)&Tl[1][(yy * 32 + xx) * 16] = z;
            *(f16x8*)&Tl[1][(yy * 32 + xx) * 16 + 8] = z;
        }
    }

    auto stage = [&](int cg, int bufn) {
        if (tid < 392) {
            int p = tid >> 1, oc = tid & 1;
            int ch0 = cg * 16 + oc * 8;
            int c2 = ch0 / 104, rr = ch0 % 104, ii = rr >> 3;
            float h = h1p[((size_t)b * 13 + ii) * 196 + p];
            float s1, c1;
            __sincosf(h, &s1, &c1);
            f16x8 v;
            float ck = c1, sk = s1, ckm = 1.f, skm = 0.f;
#pragma unroll
            for (int g = 0; g < 8; ++g) {
                v[g] = (f16)(c2 == 0 ? ck : sk);
                float cn = 2.f * c1 * ck - ckm;
                float sn2 = 2.f * c1 * sk - skm;
                ckm = ck; ck = cn; skm = sk; sk = sn2;
            }
            int y = p / 14, xp = p - y * 14;
            *(f16x8*)&Tl[bufn][(((y + 6) * 32 + xp + 6) * 2 + oc) * 8] = v;
        }
    };

    stage(0, 0);
    f32x4 acc[14][2] = {};
    __syncthreads();

    const int nkx = (w < 5) ? 2 : 1;
    for (int cg = 0; cg < 13; ++cg) {
        const int bufn = cg & 1;
        if (cg + 1 < 13) stage(cg + 1, bufn ^ 1);
        const f16* Tb = &Tl[bufn][0];
        for (int rep = 0; rep < nkx; ++rep) {
            const int kx = w + rep * 8;
            f16x8 bf[7][2];
#pragma unroll
            for (int p = 0; p < 7; ++p)
#pragma unroll
                for (int nt = 0; nt < 2; ++nt)
                    bf[p][nt] = *(const f16x8*)&Wb2[((((size_t)(cg * 13 + kx) * 7 + p) * 2 + nt) * 64 + l) * 8];
            const int xb = col + kx;
#pragma unroll
            for (int yy0 = 0; yy0 < 26; ++yy0) {
                f16x8 a = *(const f16x8*)&Tb[(((yy0 + (oct >> 1)) * 32 + xb) * 2 + (oct & 1)) * 8];
#pragma unroll
                for (int p = 0; p < 7; ++p) {
                    const int m = yy0 - 2 * p;
                    if (m >= 0 && m < 14) {
                        acc[m][0] = __builtin_amdgcn_mfma_f32_16x16x32_f16(a, bf[p][0], acc[m][0], 0, 0, 0);
                        acc[m][1] = __builtin_amdgcn_mfma_f32_16x16x32_f16(a, bf[p][1], acc[m][1], 0, 0, 0);
                    }
                }
            }
        }
        __syncthreads();
    }

    // tree reduction: waves 0-3 -> R0, waves 4-7 -> R1
    float* R0 = (float*)&Tl[0][0];
    float* R1 = (float*)&Tl[1][0];
    float* Rw = (w < 4) ? R0 : R1;
    const int wph = w & 3;
    for (int ph = 0; ph < 4; ++ph) {
        if (wph == ph) {
#pragma unroll
            for (int m = 0; m < 14; ++m)
#pragma unroll
                for (int nt = 0; nt < 2; ++nt)
#pragma unroll
                    for (int j = 0; j < 4; ++j) {
                        int idx = (m * 16 + oct * 4 + j) * 32 + nt * 16 + col;
                        float v = acc[m][nt][j];
                        if (ph) v += Rw[idx];
                        Rw[idx] = v;
                    }
        }
        __syncthreads();
    }

    for (int idx = tid; idx < 1029; idx += 512) {
        int o = idx % 21; int r = idx / 21; int px = r % 7; int py = r / 7;
        float mx = -1e30f;
#pragma unroll
        for (int sy = 0; sy < 2; ++sy)
#pragma unroll
            for (int sx = 0; sx < 2; ++sx) {
                int ii = ((py * 2 + sy) * 16 + px * 2 + sx) * 32 + o;
                mx = fmaxf(mx, R0[ii] + R1[ii]);
            }
        h2f[(size_t)b * 1029 + o * 49 + py * 7 + px] = mx + b2[o];
    }
}

// ------------------------------------------------------------------
// K4: fk1 via MFMA.  Block = (mt8 0..7, ks 0..32): 32 images x 32 d's.
// A = trig expansion in LDS [26 kstep][32 m][32 d] f16; B pre-packed.
// 4 waves x 3 (mt,nt)-tiles; partials to P3.
// ------------------------------------------------------------------
__global__ __launch_bounds__(256) void k_fk1m(const float* __restrict__ h2f,
                                              const f16* __restrict__ Wf1b,
                                              float* __restrict__ P3) {
    __shared__ f16 A[26 * 32 * 32];
    const int bid = blockIdx.x;
    const int mt8 = bid / NCH, ks = bid % NCH;
    const int m0 = mt8 * 32, d0 = ks * 32;
    const int tid = threadIdx.x;
    const int dl = tid & 31, mb = tid >> 5;
#pragma unroll
    for (int j = 0; j < 4; ++j) {
        int m = mb + 8 * j;
        int d = d0 + dl;
        bool valid = d < 1029;
        float h = valid ? h2f[(size_t)(m0 + m) * 1029 + d] : 0.f;
        float s1, c1; sincosf(h, &s1, &c1);
        float ck = c1, sk = s1, ckm = 1.f, skm = 0.f;
#pragma unroll
        for (int g = 0; g < 13; ++g) {
            A[(g) * 1024 + m * 32 + dl]      = valid ? (f16)ck : (f16)0;
            A[(13 + g) * 1024 + m * 32 + dl] = valid ? (f16)sk : (f16)0;
            float cn = 2.f * c1 * ck - ckm;
            float sn2 = 2.f * c1 * sk - skm;
            ckm = ck; ck = cn; skm = sk; sk = sn2;
        }
    }
    __syncthreads();
    const int w = tid >> 6, l = tid & 63;
    const int mt = w >> 1, ntg = (w & 1) * 3;
    f32x4 acc[3] = {};
    for (int kstep = 0; kstep < 26; ++kstep) {
        f16x8 a = *(const f16x8*)&A[kstep * 1024 + (mt * 16 + (l & 15)) * 32 + (l >> 4) * 8];
#pragma unroll
        for (int j = 0; j < 3; ++j) {
            f16x8 bv = *(const f16x8*)&Wf1b[((((size_t)ks * 26 + kstep) * 6 + ntg + j) * 64 + l) * 8];
            acc[j] = __builtin_amdgcn_mfma_f32_16x16x32_f16(a, bv, acc[j], 0, 0, 0);
        }
    }
    const int o_base = (l & 15);
#pragma unroll
    for (int j = 0; j < 3; ++j) {
        int o = (ntg + j) * 16 + o_base;
        if (o < 89) {
#pragma unroll
            for (int jj = 0; jj < 4; ++jj) {
                int m = m0 + mt * 16 + (l >> 4) * 4 + jj;
                P3[((size_t)ks * 256 + m) * 89 + o] = acc[j][jj];
            }
        }
    }
}

// ------------------------------------------------------------------
// K5: reduce 33 fk1 partials + bias -> trig(G=8) -> fk2 -> f32 out
// ------------------------------------------------------------------
__global__ __launch_bounds__(128) void k_fk2(const float* __restrict__ P3,
                                             const float* __restrict__ bias1,
                                             const float* __restrict__ wf2,
                                             const float* __restrict__ bias2,
                                             float* __restrict__ out) {
    __shared__ float2 tcs2[89][8];
    __shared__ float part[80];
    int b = blockIdx.x, tid = threadIdx.x;
    if (tid < 89) {
        float v = bias1[tid];
        for (int ks = 0; ks < NCH; ++ks)
            v += P3[((size_t)ks * 256 + b) * 89 + tid];
#pragma unroll
        for (int g = 0; g < 8; ++g) {
            float s, c; sincosf(v * (float)(g + 1), &s, &c);
            tcs2[tid][g] = make_float2(c, s);
        }
    }
    __syncthreads();
    if (tid < 80) {
        int o = tid >> 3, g = tid & 7;
        float s = 0.f;
        for (int d = 0; d < 89; ++d) {
            float2 tv = tcs2[d][g];
            s = fmaf(tv.x, wf2[((size_t)o * 89 + d) * 8 + g],
                fmaf(tv.y, wf2[7120 + ((size_t)o * 89 + d) * 8 + g], s));
        }
        part[tid] = s;
    }
    __syncthreads();
    if (tid < 10) {
        float v = bias2[tid];
#pragma unroll
        for (int g = 0; g < 8; ++g) v += part[tid * 8 + g];
        out[b * 10 + tid] = v;
    }
}

extern "C" void kernel_launch(void* const* d_in, const int* in_sizes, int n_in,
                              void* d_out, int out_size, void* d_ws, size_t ws_size,
                              hipStream_t stream) {
    const float* x   = (const float*)d_in[0];
    const float* w1  = (const float*)d_in[1];
    const float* b1  = (const float*)d_in[2];
    const float* w2  = (const float*)d_in[3];
    const float* b2  = (const float*)d_in[4];
    const float* wf1 = (const float*)d_in[5];
    const float* bf1 = (const float*)d_in[6];
    const float* wf2 = (const float*)d_in[7];
    const float* bf2v = (const float*)d_in[8];

    char* ws  = (char*)d_ws;
    float* h1p  = (float*)(ws + H1_OFF);
    f16*   Wb2  = (f16*)(ws + WB_OFF);
    f16*   Wf1b = (f16*)(ws + WF_OFF);
    float* h2f  = (float*)(ws + H2_OFF);
    float* P3   = (float*)(ws + P3_OFF);

    k_prep_wb<<<(13 * 13 * 7 * 2 * 64 + 255) / 256, 256, 0, stream>>>(w2, Wb2);
    k_prep_wf<<<(33 * 26 * 6 * 64 + 255) / 256, 256, 0, stream>>>(wf1, Wf1b);
    k_conv1<<<512, 256, 0, stream>>>(x, w1, b1, h1p);
    k_conv2m<<<256, 512, 0, stream>>>(h1p, Wb2, b2, h2f);
    k_fk1m<<<8 * NCH, 256, 0, stream>>>(h2f, Wf1b, P3);
    k_fk2<<<256, 128, 0, stream>>>(P3, bf1, wf2, bf2v, (float*)d_out);
}

// Round 8
// 235.011 us; speedup vs baseline: 12.9405x; 1.0987x over previous
//
#include <hip/hip_runtime.h>
#include <hip/hip_bf16.h>

typedef _Float16 f16;
typedef f16  f16x8 __attribute__((ext_vector_type(8)));
typedef float f32x4 __attribute__((ext_vector_type(4)));

// ---------------- workspace layout ----------------
// h1p  : [256][13][196] f32
// Wb2  : [13cg][13kx][7p][2nt][64l][8] f16
// Wf1b : [33ks][26kstep][6nt][64l][8] f16
// Pp   : [2][256][14][14][21] f32   conv2 K-half partials
// h2f  : [256][1029] f32
// P3   : [33][256][89] f32
static constexpr size_t H1_OFF = 0;
static constexpr size_t H1_BYTES = (size_t)256 * 13 * 196 * 4;            // 2,609,152
static constexpr size_t WB_OFF = H1_OFF + H1_BYTES;
static constexpr size_t WB_BYTES = (size_t)13 * 13 * 7 * 2 * 64 * 8 * 2;  // 2,422,784
static constexpr size_t WF_OFF = WB_OFF + WB_BYTES;
static constexpr size_t WF_BYTES = (size_t)33 * 26 * 6 * 64 * 8 * 2;      // 5,271,552
static constexpr size_t PP_OFF = WF_OFF + WF_BYTES;
static constexpr size_t PP_BYTES = (size_t)2 * 256 * 14 * 14 * 21 * 4;    // 8,429,568
static constexpr size_t H2_OFF = PP_OFF + PP_BYTES;
static constexpr size_t H2_BYTES = (size_t)256 * 1029 * 4;                // 1,053,696
static constexpr size_t P3_OFF = H2_OFF + H2_BYTES;

static constexpr int NCH = 33;   // fk1 d-chunks of 32

// ------------------------------------------------------------------
// K0: conv2 B-fragments (unchanged layout).
// ------------------------------------------------------------------
__global__ __launch_bounds__(256) void k_prep_wb(const float* __restrict__ w2,
                                                 f16* __restrict__ Wb2) {
    int idx = blockIdx.x * 256 + threadIdx.x;   // 13*13*7*2*64 = 151424
    if (idx >= 13 * 13 * 7 * 2 * 64) return;
    int l = idx & 63; int t = idx >> 6;
    int nt = t & 1; t >>= 1;
    int p = t % 7; t /= 7;
    int kx = t % 13; int cg = t / 13;
    int oct = l >> 4, col = l & 15;
    int ky = 2 * p + (oct >> 1);
    int o = nt * 16 + col;
    f16x8 v;
#pragma unroll
    for (int i = 0; i < 8; ++i) {
        float wv = 0.f;
        if (ky < 13 && o < 21) {
            int ch = cg * 16 + (oct & 1) * 8 + i;
            int c2 = ch / 104, rr = ch % 104, ii = rr >> 3, gg = rr & 7;
            wv = w2[(size_t)(c2 * 21 + o) * 17576 + ii * 1352 + ky * 104 + kx * 8 + gg];
        }
        v[i] = (f16)wv;
    }
    *(f16x8*)&Wb2[(size_t)idx * 8] = v;
}

// ------------------------------------------------------------------
// K0b: fk1 B-fragments, coalesced via LDS transpose.
// block = (ks, c); reads 13-float g-runs contiguously.
// ------------------------------------------------------------------
__global__ __launch_bounds__(256) void k_prep_wf(const float* __restrict__ wf1,
                                                 f16* __restrict__ Wf1b) {
    __shared__ __align__(16) f16 Wl[13][2848];   // [g][o*32+dl]
    int bid = blockIdx.x;          // 66 = 33 ks x 2 c
    int c = bid & 1, ks = bid >> 1;
    int tid = threadIdx.x;
    for (int e = tid; e < 89 * 32; e += 256) {
        int o = e >> 5, dl = e & 31;
        int d = ks * 32 + dl;
        if (d < 1029) {
            const float* p = wf1 + ((size_t)(c * 89 + o) * 1029 + d) * 13;
#pragma unroll
            for (int g = 0; g < 13; ++g) Wl[g][e] = (f16)p[g];
        } else {
#pragma unroll
            for (int g = 0; g < 13; ++g) Wl[g][e] = (f16)0;
        }
    }
    __syncthreads();
    for (int t = tid; t < 13 * 6 * 64; t += 256) {
        int l = t & 63; int q = t >> 6; int nt = q % 6; int g = q / 6;
        int o = nt * 16 + (l & 15);
        int kbase = (l >> 4) * 8;
        f16x8 v;
#pragma unroll
        for (int i = 0; i < 8; ++i)
            v[i] = (o < 89) ? Wl[g][o * 32 + kbase + i] : (f16)0;
        *(f16x8*)&Wf1b[(((size_t)ks * 26 + c * 13 + g) * 6 + nt) * 512 + (size_t)l * 8] = v;
    }
}

// ------------------------------------------------------------------
// K1: conv1 rewrite: trig once per input pixel; conv with scalar
// (wave-uniform) weight loads; pool from LDS.  Block = (image, yhalf).
// ------------------------------------------------------------------
__global__ __launch_bounds__(256) void k_conv1(const float* __restrict__ x,
                                               const float* __restrict__ w1,
                                               const float* __restrict__ b1,
                                               float* __restrict__ h1p) {
    __shared__ float2 tcs[5][448];       // 16 input rows x 28
    __shared__ float  cv[392 * 13];      // 14 conv rows x 28 x 13
    int bid = blockIdx.x, tid = threadIdx.x;
    int b = bid >> 1, yh = bid & 1;
    int y0 = yh * 12;                    // staged input rows y0..y0+15
    const float* xb = x + (size_t)b * 784;
    for (int i = tid; i < 448; i += 256) {
        float v = xb[y0 * 28 + i];
        float s1, c1; __sincosf(v, &s1, &c1);
        float ck = c1, sk = s1, ckm = 1.f, skm = 0.f;
#pragma unroll
        for (int g = 0; g < 5; ++g) {
            tcs[g][i] = make_float2(ck, sk);
            float cn = 2.f * c1 * ck - ckm, sn = 2.f * c1 * sk - skm;
            ckm = ck; ck = cn; skm = sk; sk = sn;
        }
    }
    __syncthreads();
    for (int pp = tid; pp < 392; pp += 256) {
        int yl = pp / 28, xx = pp % 28;
        int y = yh * 14 + yl;
        float acc[13] = {};
        for (int ky = 0; ky < 5; ++ky) {
            int row = y + ky - 2;
            if ((unsigned)row >= 28u) continue;
            int lr = row - y0;
            for (int kx = 0; kx < 5; ++kx) {
                int col = xx + kx - 2;
                if ((unsigned)col >= 28u) continue;
                float2 tv[5];
#pragma unroll
                for (int g = 0; g < 5; ++g) tv[g] = tcs[g][lr * 28 + col];
#pragma unroll
                for (int o = 0; o < 13; ++o) {
                    const float* wco = w1 + (o * 25 + ky * 5 + kx) * 5;   // uniform -> s_load
                    const float* wso = wco + 1625;
                    float a = acc[o];
#pragma unroll
                    for (int g = 0; g < 5; ++g)
                        a = fmaf(tv[g].x, wco[g], fmaf(tv[g].y, wso[g], a));
                    acc[o] = a;
                }
            }
        }
#pragma unroll
        for (int o = 0; o < 13; ++o) cv[pp * 13 + o] = acc[o];
    }
    __syncthreads();
    for (int i = tid; i < 7 * 14 * 13; i += 256) {
        int o = i % 13; int r = i / 13; int px = r % 14; int pyl = r / 14;
        int base0 = ((pyl * 2) * 28 + px * 2) * 13 + o;
        float m = fmaxf(fmaxf(cv[base0], cv[base0 + 13]),
                        fmaxf(cv[base0 + 28 * 13], cv[base0 + 28 * 13 + 13]));
        int py = yh * 7 + pyl;
        h1p[((size_t)b * 13 + o) * 196 + py * 14 + px] = m + b1[o];
    }
}

// ------------------------------------------------------------------
// K2: conv2 MFMA.  Block = (image, cg-parity half): 2 blocks/CU.
// Rotating kx ownership balances waves (j0 = (w-5*ci)&7).
// Per-block partial -> Pp.
// ------------------------------------------------------------------
__global__ __launch_bounds__(512, 2) void k_conv2m(const float* __restrict__ h1p,
                                                   const f16* __restrict__ Wb2,
                                                   float* __restrict__ Pp) {
    __shared__ f16 Tl[2][28 * 32 * 16];
    const int bid = blockIdx.x;
    const int b = bid >> 1, h = bid & 1;
    const int tid = threadIdx.x;
    const int l = tid & 63, w = tid >> 6;
    const int oct = l >> 4, col = l & 15;
    const int ncg = 7 - h;

    for (int pos = tid; pos < 896; pos += 512) {
        int yy = pos >> 5, xx = pos & 31;
        if (yy < 6 || yy >= 20 || xx < 6 || xx >= 20) {
            f16x8 z = {};
            *(f16x8*)&Tl[0][(yy * 32 + xx) * 16] = z;
            *(f16x8*)&Tl[0][(yy * 32 + xx) * 16 + 8] = z;
            *(f16x8*)&Tl[1][(yy * 32 + xx) * 16] = z;
            *(f16x8*)&Tl[1][(yy * 32 + xx) * 16 + 8] = z;
        }
    }

    auto stage = [&](int cg, int bufn) {
        if (tid < 392) {
            int p = tid >> 1, oc = tid & 1;
            int ch0 = cg * 16 + oc * 8;
            int c2 = ch0 / 104, rr = ch0 % 104, ii = rr >> 3;
            float hh = h1p[((size_t)b * 13 + ii) * 196 + p];
            float s1, c1;
            __sincosf(hh, &s1, &c1);
            f16x8 v;
            float ck = c1, sk = s1, ckm = 1.f, skm = 0.f;
#pragma unroll
            for (int g = 0; g < 8; ++g) {
                v[g] = (f16)(c2 == 0 ? ck : sk);
                float cn = 2.f * c1 * ck - ckm;
                float sn2 = 2.f * c1 * sk - skm;
                ckm = ck; ck = cn; skm = sk; sk = sn2;
            }
            int y = p / 14, xp = p - y * 14;
            *(f16x8*)&Tl[bufn][(((y + 6) * 32 + xp + 6) * 2 + oc) * 8] = v;
        }
    };

    stage(h, 0);
    f32x4 acc[14][2] = {};
    __syncthreads();

    for (int ci = 0; ci < ncg; ++ci) {
        const int bufn = ci & 1;
        const int cg = h + 2 * ci;
        if (ci + 1 < ncg) stage(cg + 2, bufn ^ 1);
        const f16* Tb = &Tl[bufn][0];
        const int j0 = (w - 5 * ci) & 7;
        const int nrep = (j0 < 5) ? 2 : 1;
        for (int rep = 0; rep < nrep; ++rep) {
            const int kx = j0 + rep * 8;
            f16x8 bf[7][2];
#pragma unroll
            for (int p = 0; p < 7; ++p)
#pragma unroll
                for (int nt = 0; nt < 2; ++nt)
                    bf[p][nt] = *(const f16x8*)&Wb2[((((size_t)(cg * 13 + kx) * 7 + p) * 2 + nt) * 64 + l) * 8];
            const int xb2 = col + kx;
#pragma unroll
            for (int yy0 = 0; yy0 < 26; ++yy0) {
                f16x8 a = *(const f16x8*)&Tb[(((yy0 + (oct >> 1)) * 32 + xb2) * 2 + (oct & 1)) * 8];
#pragma unroll
                for (int p = 0; p < 7; ++p) {
                    const int m = yy0 - 2 * p;
                    if (m >= 0 && m < 14) {
                        acc[m][0] = __builtin_amdgcn_mfma_f32_16x16x32_f16(a, bf[p][0], acc[m][0], 0, 0, 0);
                        acc[m][1] = __builtin_amdgcn_mfma_f32_16x16x32_f16(a, bf[p][1], acc[m][1], 0, 0, 0);
                    }
                }
            }
        }
        __syncthreads();
    }

    float* R0 = (float*)&Tl[0][0];
    float* R1 = (float*)&Tl[1][0];
    float* Rw = (w < 4) ? R0 : R1;
    const int wph = w & 3;
    for (int ph = 0; ph < 4; ++ph) {
        if (wph == ph) {
#pragma unroll
            for (int m = 0; m < 14; ++m)
#pragma unroll
                for (int nt = 0; nt < 2; ++nt)
#pragma unroll
                    for (int j = 0; j < 4; ++j) {
                        int idx = (m * 16 + oct * 4 + j) * 32 + nt * 16 + col;
                        float v = acc[m][nt][j];
                        if (ph) v += Rw[idx];
                        Rw[idx] = v;
                    }
        }
        __syncthreads();
    }

    float* P = Pp + ((size_t)h * 256 + b) * 4116;
    for (int idx = tid; idx < 4116; idx += 512) {
        int o = idx % 21; int r2 = idx / 21; int rr = r2 % 14; int m = r2 / 14;
        int ii = (m * 16 + rr) * 32 + o;
        P[idx] = R0[ii] + R1[ii];
    }
}

// ------------------------------------------------------------------
// K3: sum 2 K-half partials + maxpool + bias -> h2f
// ------------------------------------------------------------------
__global__ __launch_bounds__(256) void k_pool2(const float* __restrict__ Pp,
                                               const float* __restrict__ b2,
                                               float* __restrict__ h2f) {
    int b = blockIdx.x, tid = threadIdx.x;
    const float* P0 = Pp + (size_t)b * 4116;
    const float* P1 = Pp + ((size_t)256 + b) * 4116;
    for (int idx = tid; idx < 1029; idx += 256) {
        int o = idx % 21; int r = idx / 21; int px = r % 7; int py = r / 7;
        float mx = -1e30f;
#pragma unroll
        for (int sy = 0; sy < 2; ++sy)
#pragma unroll
            for (int sx = 0; sx < 2; ++sx) {
                int ii = ((py * 2 + sy) * 14 + px * 2 + sx) * 21 + o;
                mx = fmaxf(mx, P0[ii] + P1[ii]);
            }
        h2f[(size_t)b * 1029 + o * 49 + py * 7 + px] = mx + b2[o];
    }
}

// ------------------------------------------------------------------
// K4: fk1 via MFMA (unchanged).
// ------------------------------------------------------------------
__global__ __launch_bounds__(256) void k_fk1m(const float* __restrict__ h2f,
                                              const f16* __restrict__ Wf1b,
                                              float* __restrict__ P3) {
    __shared__ f16 A[26 * 32 * 32];
    const int bid = blockIdx.x;
    const int mt8 = bid / NCH, ks = bid % NCH;
    const int m0 = mt8 * 32, d0 = ks * 32;
    const int tid = threadIdx.x;
    const int dl = tid & 31, mb = tid >> 5;
#pragma unroll
    for (int j = 0; j < 4; ++j) {
        int m = mb + 8 * j;
        int d = d0 + dl;
        bool valid = d < 1029;
        float h = valid ? h2f[(size_t)(m0 + m) * 1029 + d] : 0.f;
        float s1, c1; __sincosf(h, &s1, &c1);
        float ck = c1, sk = s1, ckm = 1.f, skm = 0.f;
#pragma unroll
        for (int g = 0; g < 13; ++g) {
            A[(g) * 1024 + m * 32 + dl]      = valid ? (f16)ck : (f16)0;
            A[(13 + g) * 1024 + m * 32 + dl] = valid ? (f16)sk : (f16)0;
            float cn = 2.f * c1 * ck - ckm;
            float sn2 = 2.f * c1 * sk - skm;
            ckm = ck; ck = cn; skm = sk; sk = sn2;
        }
    }
    __syncthreads();
    const int w = tid >> 6, l = tid & 63;
    const int mt = w >> 1, ntg = (w & 1) * 3;
    f32x4 acc[3] = {};
    for (int kstep = 0; kstep < 26; ++kstep) {
        f16x8 a = *(const f16x8*)&A[kstep * 1024 + (mt * 16 + (l & 15)) * 32 + (l >> 4) * 8];
#pragma unroll
        for (int j = 0; j < 3; ++j) {
            f16x8 bv = *(const f16x8*)&Wf1b[((((size_t)ks * 26 + kstep) * 6 + ntg + j) * 64 + l) * 8];
            acc[j] = __builtin_amdgcn_mfma_f32_16x16x32_f16(a, bv, acc[j], 0, 0, 0);
        }
    }
    const int o_base = (l & 15);
#pragma unroll
    for (int j = 0; j < 3; ++j) {
        int o = (ntg + j) * 16 + o_base;
        if (o < 89) {
#pragma unroll
            for (int jj = 0; jj < 4; ++jj) {
                int m = m0 + mt * 16 + (l >> 4) * 4 + jj;
                P3[((size_t)ks * 256 + m) * 89 + o] = acc[j][jj];
            }
        }
    }
}

// ------------------------------------------------------------------
// K5: reduce 33 fk1 partials + bias -> trig(G=8) -> fk2 -> f32 out
// ------------------------------------------------------------------
__global__ __launch_bounds__(128) void k_fk2(const float* __restrict__ P3,
                                             const float* __restrict__ bias1,
                                             const float* __restrict__ wf2,
                                             const float* __restrict__ bias2,
                                             float* __restrict__ out) {
    __shared__ float2 tcs2[89][8];
    __shared__ float part[80];
    int b = blockIdx.x, tid = threadIdx.x;
    if (tid < 89) {
        float v = bias1[tid];
        for (int ks = 0; ks < NCH; ++ks)
            v += P3[((size_t)ks * 256 + b) * 89 + tid];
#pragma unroll
        for (int g = 0; g < 8; ++g) {
            float s, c; __sincosf(v * (float)(g + 1), &s, &c);
            tcs2[tid][g] = make_float2(c, s);
        }
    }
    __syncthreads();
    if (tid < 80) {
        int o = tid >> 3, g = tid & 7;
        float s = 0.f;
        for (int d = 0; d < 89; ++d) {
            float2 tv = tcs2[d][g];
            s = fmaf(tv.x, wf2[((size_t)o * 89 + d) * 8 + g],
                fmaf(tv.y, wf2[7120 + ((size_t)o * 89 + d) * 8 + g], s));
        }
        part[tid] = s;
    }
    __syncthreads();
    if (tid < 10) {
        float v = bias2[tid];
#pragma unroll
        for (int g = 0; g < 8; ++g) v += part[tid * 8 + g];
        out[b * 10 + tid] = v;
    }
}

extern "C" void kernel_launch(void* const* d_in, const int* in_sizes, int n_in,
                              void* d_out, int out_size, void* d_ws, size_t ws_size,
                              hipStream_t stream) {
    const float* x   = (const float*)d_in[0];
    const float* w1  = (const float*)d_in[1];
    const float* b1  = (const float*)d_in[2];
    const float* w2  = (const float*)d_in[3];
    const float* b2  = (const float*)d_in[4];
    const float* wf1 = (const float*)d_in[5];
    const float* bf1 = (const float*)d_in[6];
    const float* wf2 = (const float*)d_in[7];
    const float* bf2v = (const float*)d_in[8];

    char* ws  = (char*)d_ws;
    float* h1p  = (float*)(ws + H1_OFF);
    f16*   Wb2  = (f16*)(ws + WB_OFF);
    f16*   Wf1b = (f16*)(ws + WF_OFF);
    float* Pp   = (float*)(ws + PP_OFF);
    float* h2f  = (float*)(ws + H2_OFF);
    float* P3   = (float*)(ws + P3_OFF);

    k_prep_wb<<<(13 * 13 * 7 * 2 * 64 + 255) / 256, 256, 0, stream>>>(w2, Wb2);
    k_prep_wf<<<66, 256, 0, stream>>>(wf1, Wf1b);
    k_conv1<<<512, 256, 0, stream>>>(x, w1, b1, h1p);
    k_conv2m<<<512, 512, 0, stream>>>(h1p, Wb2, Pp);
    k_pool2<<<256, 256, 0, stream>>>(Pp, b2, h2f);
    k_fk1m<<<8 * NCH, 256, 0, stream>>>(h2f, Wf1b, P3);
    k_fk2<<<256, 128, 0, stream>>>(P3, bf1, wf2, bf2v, (float*)d_out);
}